// Round 6
// baseline (306.665 us; speedup 1.0000x reference)
//
#include <hip/hip_runtime.h>
#include <hip/hip_bf16.h>

constexpr int NROW = 8192;
constexpr int INF  = 256;
constexpr int OUTF = 128;
constexpr int KSPLIT = 32;
constexpr int KCHUNK = NROW / KSPLIT; // 256
#define LOG2E 1.4426950408889634f

typedef __bf16 bf16x8 __attribute__((ext_vector_type(8)));
typedef float  f32x4  __attribute__((ext_vector_type(4)));
typedef int    i32x4  __attribute__((ext_vector_type(4)));
typedef unsigned long long u64;

// ---------------------------------------------------------------------------
// k1: h = x@W (f32 accum); f1 = (h@a1)*log2e, f2 = (h@a2)*log2e; ht = h^T bf16
// grid: NROW/32 blocks, 256 threads
// ---------------------------------------------------------------------------
__global__ __launch_bounds__(256) void k1(const float* __restrict__ x,
                                          const float* __restrict__ W,
                                          const float* __restrict__ a,
                                          __bf16* __restrict__ ht,
                                          float* __restrict__ f1,
                                          float* __restrict__ f2) {
  __shared__ float xs[32][INF];   // 32 KB
  __shared__ float hs[32][OUTF];  // 16 KB
  const int t  = threadIdx.x;
  const int i0 = blockIdx.x * 32;

  const f32x4* xsrc = reinterpret_cast<const f32x4*>(x + (size_t)i0 * INF);
  f32x4* xdst = reinterpret_cast<f32x4*>(&xs[0][0]);
  #pragma unroll
  for (int u = 0; u < (32 * INF / 4) / 256; ++u)
    xdst[u * 256 + t] = xsrc[u * 256 + t];
  __syncthreads();

  const int c  = t & 127;
  const int rg = t >> 7;  // 0/1 -> rows rg*16 .. rg*16+15
  float acc[16];
  #pragma unroll
  for (int r = 0; r < 16; ++r) acc[r] = 0.f;
  for (int k = 0; k < INF; ++k) {
    float wv = W[k * OUTF + c];
    #pragma unroll
    for (int r = 0; r < 16; ++r) acc[r] += xs[rg * 16 + r][k] * wv;
  }
  #pragma unroll
  for (int r = 0; r < 16; ++r) hs[rg * 16 + r][c] = acc[r];
  __syncthreads();

  const int wv = t >> 6, lane = t & 63;
  for (int r = wv; r < 32; r += 4) {
    float h0 = hs[r][lane * 2], h1 = hs[r][lane * 2 + 1];
    float s1 = h0 * a[lane * 2] + h1 * a[lane * 2 + 1];
    float s2 = h0 * a[OUTF + lane * 2] + h1 * a[OUTF + lane * 2 + 1];
    #pragma unroll
    for (int off = 32; off; off >>= 1) {
      s1 += __shfl_down(s1, off);
      s2 += __shfl_down(s2, off);
    }
    if (lane == 0) { f1[i0 + r] = s1 * LOG2E; f2[i0 + r] = s2 * LOG2E; }
  }

  const int col = t >> 1, seg = t & 1;
  bf16x8 v0, v1;
  #pragma unroll
  for (int r = 0; r < 8; ++r) v0[r] = (__bf16)hs[seg * 16 + r][col];
  #pragma unroll
  for (int r = 0; r < 8; ++r) v1[r] = (__bf16)hs[seg * 16 + 8 + r][col];
  __bf16* hdst = ht + (size_t)col * NROW + i0 + seg * 16;
  *reinterpret_cast<bf16x8*>(hdst)     = v0;
  *reinterpret_cast<bf16x8*>(hdst + 8) = v1;
}

// ---------------------------------------------------------------------------
// k2: one wave per row, 512 cols/iter, regular (cached) int4 loads. Nibble-
// pack mask via __shfl_xor OR-reduce; row sum of masked exp2.
// grid: NROW/4 blocks, 256 threads
// ---------------------------------------------------------------------------
__global__ __launch_bounds__(256) void k2(const int* __restrict__ adj,
                                          const float* __restrict__ f1,
                                          const float* __restrict__ f2,
                                          u64* __restrict__ mask,
                                          float* __restrict__ s) {
  const int row  = blockIdx.x * 4 + (threadIdx.x >> 6);
  const int lane = threadIdx.x & 63;
  const float f1i = f1[row];
  const i32x4* arow = reinterpret_cast<const i32x4*>(adj + (size_t)row * NROW);
  const f32x4* f2v  = reinterpret_cast<const f32x4*>(f2);

  float acc = 0.f;
  for (int it = 0; it < NROW / 512; ++it) {
    i32x4 av0 = arow[it * 128 + lane];
    i32x4 av1 = arow[it * 128 + 64 + lane];
    f32x4 fv0 = f2v[it * 128 + lane];
    f32x4 fv1 = f2v[it * 128 + 64 + lane];

    unsigned nib0 = (av0[0] > 0) | ((av0[1] > 0) << 1) | ((av0[2] > 0) << 2) |
                    ((av0[3] > 0) << 3);
    unsigned nib1 = (av1[0] > 0) | ((av1[1] > 0) << 1) | ((av1[2] > 0) << 2) |
                    ((av1[3] > 0) << 3);
    #pragma unroll
    for (int b = 0; b < 4; ++b) {
      float e0 = f1i + fv0[b];
      e0 = e0 > 0.f ? e0 : 0.01f * e0;
      acc += ((nib0 >> b) & 1u) ? __builtin_exp2f(e0) : 0.f;
      float e1 = f1i + fv1[b];
      e1 = e1 > 0.f ? e1 : 0.01f * e1;
      acc += ((nib1 >> b) & 1u) ? __builtin_exp2f(e1) : 0.f;
    }
    u64 m0 = (u64)nib0 << (4 * (lane & 15));
    u64 m1 = (u64)nib1 << (4 * (lane & 15));
    #pragma unroll
    for (int d = 1; d < 16; d <<= 1) {
      m0 |= __shfl_xor(m0, d);
      m1 |= __shfl_xor(m1, d);
    }
    if ((lane & 15) == 0) {
      mask[(size_t)row * 128 + it * 8 + (lane >> 4)]     = m0;
      mask[(size_t)row * 128 + it * 8 + 4 + (lane >> 4)] = m1;
    }
  }
  #pragma unroll
  for (int off = 32; off; off >>= 1) acc += __shfl_down(acc, off);
  if (lane == 0) s[row] = acc;
}

// ---------------------------------------------------------------------------
// k3: fused att-write + PV. 64 rows x 256-col chunk per block (KSPLIT=32 ->
// 4096 blocks = 8 blocks/CU co-resident = 32 waves/CU, latency-hiding fix).
// grid: (NROW/64)*KSPLIT blocks, 256 threads
// ---------------------------------------------------------------------------
__global__ __launch_bounds__(256, 4) void k3(const __bf16* __restrict__ ht,
                                             const float* __restrict__ f1,
                                             const float* __restrict__ f2,
                                             const float* __restrict__ sum,
                                             const u64* __restrict__ mask,
                                             float* __restrict__ out0,
                                             float* __restrict__ att) {
  __shared__ float f2s[KCHUNK];  // 1 KB
  const int mb = blockIdx.x / KSPLIT;
  const int ks = blockIdx.x % KSPLIT;
  const int t    = threadIdx.x;
  const int w    = t >> 6;
  const int lane = t & 63;
  const int lr = lane & 15;
  const int lc = lane >> 4;
  const int row0 = mb * 64 + w * 16;
  const int arow = row0 + lr;
  const int j0 = ks * KCHUNK;

  if (t < KCHUNK / 4) {
    const f32x4* src = reinterpret_cast<const f32x4*>(f2 + j0);
    reinterpret_cast<f32x4*>(f2s)[t] = src[t];
  }
  __syncthreads();

  const float f1r    = f1[arow];
  const float inv_sA = 1.0f / sum[arow];
  const u64* mrow = mask + (size_t)arow * 128 + (j0 >> 6);
  const __bf16* hbase = ht + (size_t)lr * NROW + j0 + lc * 8;
  float* arowp = att + (size_t)arow * NROW + j0 + lc * 8;

  f32x4 acc[8];
  #pragma unroll
  for (int n = 0; n < 8; ++n) acc[n] = (f32x4){0.f, 0.f, 0.f, 0.f};

  #pragma unroll
  for (int kk = 0; kk < KCHUNK; kk += 64) {
    const u64 mw = mrow[kk >> 6];
    bf16x8 afrag[2];
    #pragma unroll
    for (int h = 0; h < 2; ++h) {
      const unsigned bits = (unsigned)(mw >> (h * 32 + lc * 8)) & 0xFFu;
      const int base = kk + h * 32 + lc * 8;
      f32x4 o0, o1;
      #pragma unroll
      for (int i2 = 0; i2 < 8; ++i2) {
        float e = f1r + f2s[base + i2];
        e = e > 0.f ? e : 0.01f * e;
        float p = ((bits >> i2) & 1u) ? __builtin_exp2f(e) : 0.f;
        if (i2 < 4) o0[i2] = p * inv_sA; else o1[i2 - 4] = p * inv_sA;
        afrag[h][i2] = (__bf16)p;
      }
      // regular cached stores: L2 merges partial lines, full-line writeback
      *reinterpret_cast<f32x4*>(arowp + kk + h * 32)     = o0;
      *reinterpret_cast<f32x4*>(arowp + kk + h * 32 + 4) = o1;
    }
    #pragma unroll
    for (int n = 0; n < 8; ++n) {
      const __bf16* hb = hbase + (size_t)(n * 16) * NROW + kk;
      bf16x8 b0 = *reinterpret_cast<const bf16x8*>(hb);
      bf16x8 b1 = *reinterpret_cast<const bf16x8*>(hb + 32);
      acc[n] = __builtin_amdgcn_mfma_f32_16x16x32_bf16(afrag[0], b0, acc[n], 0, 0, 0);
      acc[n] = __builtin_amdgcn_mfma_f32_16x16x32_bf16(afrag[1], b1, acc[n], 0, 0, 0);
    }
  }

  float inv_sD[4];
  #pragma unroll
  for (int i2 = 0; i2 < 4; ++i2) inv_sD[i2] = 1.0f / sum[row0 + lc * 4 + i2];
  #pragma unroll
  for (int n = 0; n < 8; ++n) {
    #pragma unroll
    for (int i2 = 0; i2 < 4; ++i2) {
      atomicAdd(&out0[(size_t)(row0 + lc * 4 + i2) * OUTF + n * 16 + lr],
                acc[n][i2] * inv_sD[i2]);
    }
  }
}

// ---------------------------------------------------------------------------
extern "C" void kernel_launch(void* const* d_in, const int* in_sizes, int n_in,
                              void* d_out, int out_size, void* d_ws, size_t ws_size,
                              hipStream_t stream) {
  const float* x   = (const float*)d_in[0];
  const int*   adj = (const int*)d_in[1];
  const float* W   = (const float*)d_in[2];
  const float* a   = (const float*)d_in[3];

  float* out0 = (float*)d_out;                       // 8192 x 128
  float* att  = (float*)d_out + (size_t)NROW * OUTF; // 8192 x 8192

  char* ws = (char*)d_ws;
  __bf16* ht = (__bf16*)ws;                                         // 2 MB
  u64* mask = (u64*)(ws + (2 << 20));                               // 8 MB
  float* f1 = (float*)(ws + (10 << 20));
  float* f2 = (float*)(ws + (10 << 20) + 32 * 1024);
  float* s  = (float*)(ws + (10 << 20) + 64 * 1024);

  hipMemsetAsync(out0, 0, (size_t)NROW * OUTF * sizeof(float), stream);
  k1<<<NROW / 32, 256, 0, stream>>>(x, W, a, ht, f1, f2);
  k2<<<NROW / 4, 256, 0, stream>>>(adj, f1, f2, mask, s);
  k3<<<(NROW / 64) * KSPLIT, 256, 0, stream>>>(ht, f1, f2, s, mask, out0, att);
}

// Round 7
// 239.721 us; speedup vs baseline: 1.2793x; 1.2793x over previous
//
#include <hip/hip_runtime.h>
#include <hip/hip_bf16.h>

constexpr int NROW = 8192;
constexpr int INF  = 256;
constexpr int OUTF = 128;
constexpr int KSPLIT = 8;
constexpr int KCHUNK = NROW / KSPLIT; // 1024
#define LOG2E 1.4426950408889634f

typedef __bf16 bf16x8 __attribute__((ext_vector_type(8)));
typedef float  f32x4  __attribute__((ext_vector_type(4)));
typedef int    i32x4  __attribute__((ext_vector_type(4)));
typedef unsigned long long u64;

// ---------------------------------------------------------------------------
// k1: h = x@W (f32 accum); f1 = (h@a1)*log2e, f2 = (h@a2)*log2e; ht = h^T bf16
// grid: NROW/32 blocks, 256 threads
// ---------------------------------------------------------------------------
__global__ __launch_bounds__(256) void k1(const float* __restrict__ x,
                                          const float* __restrict__ W,
                                          const float* __restrict__ a,
                                          __bf16* __restrict__ ht,
                                          float* __restrict__ f1,
                                          float* __restrict__ f2) {
  __shared__ float xs[32][INF];   // 32 KB
  __shared__ float hs[32][OUTF];  // 16 KB
  const int t  = threadIdx.x;
  const int i0 = blockIdx.x * 32;

  const f32x4* xsrc = reinterpret_cast<const f32x4*>(x + (size_t)i0 * INF);
  f32x4* xdst = reinterpret_cast<f32x4*>(&xs[0][0]);
  #pragma unroll
  for (int u = 0; u < (32 * INF / 4) / 256; ++u)
    xdst[u * 256 + t] = xsrc[u * 256 + t];
  __syncthreads();

  const int c  = t & 127;
  const int rg = t >> 7;  // 0/1 -> rows rg*16 .. rg*16+15
  float acc[16];
  #pragma unroll
  for (int r = 0; r < 16; ++r) acc[r] = 0.f;
  for (int k = 0; k < INF; ++k) {
    float wv = W[k * OUTF + c];
    #pragma unroll
    for (int r = 0; r < 16; ++r) acc[r] += xs[rg * 16 + r][k] * wv;
  }
  #pragma unroll
  for (int r = 0; r < 16; ++r) hs[rg * 16 + r][c] = acc[r];
  __syncthreads();

  const int wv = t >> 6, lane = t & 63;
  for (int r = wv; r < 32; r += 4) {
    float h0 = hs[r][lane * 2], h1 = hs[r][lane * 2 + 1];
    float s1 = h0 * a[lane * 2] + h1 * a[lane * 2 + 1];
    float s2 = h0 * a[OUTF + lane * 2] + h1 * a[OUTF + lane * 2 + 1];
    #pragma unroll
    for (int off = 32; off; off >>= 1) {
      s1 += __shfl_down(s1, off);
      s2 += __shfl_down(s2, off);
    }
    if (lane == 0) { f1[i0 + r] = s1 * LOG2E; f2[i0 + r] = s2 * LOG2E; }
  }

  const int col = t >> 1, seg = t & 1;
  bf16x8 v0, v1;
  #pragma unroll
  for (int r = 0; r < 8; ++r) v0[r] = (__bf16)hs[seg * 16 + r][col];
  #pragma unroll
  for (int r = 0; r < 8; ++r) v1[r] = (__bf16)hs[seg * 16 + 8 + r][col];
  __bf16* hdst = ht + (size_t)col * NROW + i0 + seg * 16;
  *reinterpret_cast<bf16x8*>(hdst)     = v0;
  *reinterpret_cast<bf16x8*>(hdst + 8) = v1;
}

// ---------------------------------------------------------------------------
// k2: one wave per row, 512 cols/iter (2 int4 NT loads in flight). Nibble-
// pack mask via __shfl_xor OR-reduce; row sum of masked exp2.
// grid: NROW/4 blocks, 256 threads
// ---------------------------------------------------------------------------
__global__ __launch_bounds__(256) void k2(const int* __restrict__ adj,
                                          const float* __restrict__ f1,
                                          const float* __restrict__ f2,
                                          u64* __restrict__ mask,
                                          float* __restrict__ s) {
  const int row  = blockIdx.x * 4 + (threadIdx.x >> 6);
  const int lane = threadIdx.x & 63;
  const float f1i = f1[row];
  const i32x4* arow = reinterpret_cast<const i32x4*>(adj + (size_t)row * NROW);
  const f32x4* f2v  = reinterpret_cast<const f32x4*>(f2);

  float acc = 0.f;
  for (int it = 0; it < NROW / 512; ++it) {
    i32x4 av0 = __builtin_nontemporal_load(arow + it * 128 + lane);
    i32x4 av1 = __builtin_nontemporal_load(arow + it * 128 + 64 + lane);
    f32x4 fv0 = f2v[it * 128 + lane];
    f32x4 fv1 = f2v[it * 128 + 64 + lane];

    unsigned nib0 = (av0[0] > 0) | ((av0[1] > 0) << 1) | ((av0[2] > 0) << 2) |
                    ((av0[3] > 0) << 3);
    unsigned nib1 = (av1[0] > 0) | ((av1[1] > 0) << 1) | ((av1[2] > 0) << 2) |
                    ((av1[3] > 0) << 3);
    #pragma unroll
    for (int b = 0; b < 4; ++b) {
      float e0 = f1i + fv0[b];
      e0 = e0 > 0.f ? e0 : 0.01f * e0;
      acc += ((nib0 >> b) & 1u) ? __builtin_exp2f(e0) : 0.f;
      float e1 = f1i + fv1[b];
      e1 = e1 > 0.f ? e1 : 0.01f * e1;
      acc += ((nib1 >> b) & 1u) ? __builtin_exp2f(e1) : 0.f;
    }
    u64 m0 = (u64)nib0 << (4 * (lane & 15));
    u64 m1 = (u64)nib1 << (4 * (lane & 15));
    #pragma unroll
    for (int d = 1; d < 16; d <<= 1) {
      m0 |= __shfl_xor(m0, d);
      m1 |= __shfl_xor(m1, d);
    }
    if ((lane & 15) == 0) {
      mask[(size_t)row * 128 + it * 8 + (lane >> 4)]     = m0;
      mask[(size_t)row * 128 + it * 8 + 4 + (lane >> 4)] = m1;
    }
  }
  #pragma unroll
  for (int off = 32; off; off >>= 1) acc += __shfl_down(acc, off);
  if (lane == 0) s[row] = acc;
}

// ---------------------------------------------------------------------------
// k3: fused att-write + PV. 64 rows x 1024-col chunk per block. The block's
// ENTIRE mask chunk (64 rows x 16 u64 = 8 KB) is staged into LDS upfront, so
// the per-iteration exp2 dependency chain starts from a ds_read (lgkmcnt) --
// NOT a global load that would serialize behind the previous iteration's att
// stores in the in-order vmcnt queue. Remaining global ops in the loop (ht
// b-loads, att stores) are independent and pipeline freely.
// grid: (NROW/64)*KSPLIT blocks, 256 threads
// ---------------------------------------------------------------------------
__global__ __launch_bounds__(256, 4) void k3(const __bf16* __restrict__ ht,
                                             const float* __restrict__ f1,
                                             const float* __restrict__ f2,
                                             const float* __restrict__ sum,
                                             const u64* __restrict__ mask,
                                             float* __restrict__ out0,
                                             float* __restrict__ att) {
  __shared__ float f2s[KCHUNK];  // 4 KB
  __shared__ u64 ms[64][17];     // 8.5 KB (pad 17: conflict-free b64 reads)
  const int mb = blockIdx.x / KSPLIT;
  const int ks = blockIdx.x % KSPLIT;
  const int t    = threadIdx.x;
  const int w    = t >> 6;
  const int lane = t & 63;
  const int lr = lane & 15;
  const int lc = lane >> 4;
  const int row0 = mb * 64 + w * 16;
  const int arow = row0 + lr;
  const int j0 = ks * KCHUNK;

  {
    const f32x4* src = reinterpret_cast<const f32x4*>(f2 + j0);
    reinterpret_cast<f32x4*>(f2s)[t] = src[t];  // 256 x 16B = 4 KB
    // mask stage: thread t -> row t>>2, words (t&3)*4 .. +3 (32B contiguous)
    const int r = t >> 2, q = (t & 3) * 4;
    const u64* msrc = mask + (size_t)(mb * 64 + r) * 128 + (j0 >> 6) + q;
    ms[r][q]     = msrc[0];
    ms[r][q + 1] = msrc[1];
    ms[r][q + 2] = msrc[2];
    ms[r][q + 3] = msrc[3];
  }
  __syncthreads();

  const float f1r    = f1[arow];
  const float inv_sA = 1.0f / sum[arow];
  const int   rloc   = w * 16 + lr;
  const __bf16* hbase = ht + (size_t)lr * NROW + j0 + lc * 8;
  float* arowp = att + (size_t)arow * NROW + j0 + lc * 8;

  f32x4 acc[8];
  #pragma unroll
  for (int n = 0; n < 8; ++n) acc[n] = (f32x4){0.f, 0.f, 0.f, 0.f};

  for (int kk = 0; kk < KCHUNK; kk += 64) {
    const u64 mw = ms[rloc][kk >> 6];   // LDS: off the vmcnt path
    bf16x8 afrag[2];
    #pragma unroll
    for (int h = 0; h < 2; ++h) {
      const unsigned bits = (unsigned)(mw >> (h * 32 + lc * 8)) & 0xFFu;
      const int base = kk + h * 32 + lc * 8;
      f32x4 o0, o1;
      #pragma unroll
      for (int i2 = 0; i2 < 8; ++i2) {
        float e = f1r + f2s[base + i2];
        e = e > 0.f ? e : 0.01f * e;
        float p = ((bits >> i2) & 1u) ? __builtin_exp2f(e) : 0.f;
        if (i2 < 4) o0[i2] = p * inv_sA; else o1[i2 - 4] = p * inv_sA;
        afrag[h][i2] = (__bf16)p;
      }
      // regular cached stores: L2 merges partial lines, full-line writeback
      *reinterpret_cast<f32x4*>(arowp + kk + h * 32)     = o0;
      *reinterpret_cast<f32x4*>(arowp + kk + h * 32 + 4) = o1;
    }
    #pragma unroll
    for (int n = 0; n < 8; ++n) {
      const __bf16* hb = hbase + (size_t)(n * 16) * NROW + kk;
      bf16x8 b0 = *reinterpret_cast<const bf16x8*>(hb);
      bf16x8 b1 = *reinterpret_cast<const bf16x8*>(hb + 32);
      acc[n] = __builtin_amdgcn_mfma_f32_16x16x32_bf16(afrag[0], b0, acc[n], 0, 0, 0);
      acc[n] = __builtin_amdgcn_mfma_f32_16x16x32_bf16(afrag[1], b1, acc[n], 0, 0, 0);
    }
  }

  float inv_sD[4];
  #pragma unroll
  for (int i2 = 0; i2 < 4; ++i2) inv_sD[i2] = 1.0f / sum[row0 + lc * 4 + i2];
  #pragma unroll
  for (int n = 0; n < 8; ++n) {
    #pragma unroll
    for (int i2 = 0; i2 < 4; ++i2) {
      atomicAdd(&out0[(size_t)(row0 + lc * 4 + i2) * OUTF + n * 16 + lr],
                acc[n][i2] * inv_sD[i2]);
    }
  }
}

// ---------------------------------------------------------------------------
extern "C" void kernel_launch(void* const* d_in, const int* in_sizes, int n_in,
                              void* d_out, int out_size, void* d_ws, size_t ws_size,
                              hipStream_t stream) {
  const float* x   = (const float*)d_in[0];
  const int*   adj = (const int*)d_in[1];
  const float* W   = (const float*)d_in[2];
  const float* a   = (const float*)d_in[3];

  float* out0 = (float*)d_out;                       // 8192 x 128
  float* att  = (float*)d_out + (size_t)NROW * OUTF; // 8192 x 8192

  char* ws = (char*)d_ws;
  __bf16* ht = (__bf16*)ws;                                         // 2 MB
  u64* mask = (u64*)(ws + (2 << 20));                               // 8 MB
  float* f1 = (float*)(ws + (10 << 20));
  float* f2 = (float*)(ws + (10 << 20) + 32 * 1024);
  float* s  = (float*)(ws + (10 << 20) + 64 * 1024);

  hipMemsetAsync(out0, 0, (size_t)NROW * OUTF * sizeof(float), stream);
  k1<<<NROW / 32, 256, 0, stream>>>(x, W, a, ht, f1, f2);
  k2<<<NROW / 4, 256, 0, stream>>>(adj, f1, f2, mask, s);
  k3<<<(NROW / 64) * KSPLIT, 256, 0, stream>>>(ht, f1, f2, s, mask, out0, att);
}

// Round 8
// 233.789 us; speedup vs baseline: 1.3117x; 1.0254x over previous
//
#include <hip/hip_runtime.h>
#include <hip/hip_bf16.h>

constexpr int NROW = 8192;
constexpr int INF  = 256;
constexpr int OUTF = 128;
constexpr int KSPLIT = 8;
constexpr int KCHUNK = NROW / KSPLIT; // 1024
#define LOG2E 1.4426950408889634f

typedef __bf16 bf16x8 __attribute__((ext_vector_type(8)));
typedef float  f32x4  __attribute__((ext_vector_type(4)));
typedef int    i32x4  __attribute__((ext_vector_type(4)));
typedef unsigned long long u64;

// ---------------------------------------------------------------------------
// k1: h = x@W (f32 accum); f1 = (h@a1)*log2e, f2 = (h@a2)*log2e; ht = h^T bf16
// grid: NROW/32 blocks, 256 threads
// ---------------------------------------------------------------------------
__global__ __launch_bounds__(256) void k1(const float* __restrict__ x,
                                          const float* __restrict__ W,
                                          const float* __restrict__ a,
                                          __bf16* __restrict__ ht,
                                          float* __restrict__ f1,
                                          float* __restrict__ f2) {
  __shared__ float xs[32][INF];   // 32 KB
  __shared__ float hs[32][OUTF];  // 16 KB
  const int t  = threadIdx.x;
  const int i0 = blockIdx.x * 32;

  const f32x4* xsrc = reinterpret_cast<const f32x4*>(x + (size_t)i0 * INF);
  f32x4* xdst = reinterpret_cast<f32x4*>(&xs[0][0]);
  #pragma unroll
  for (int u = 0; u < (32 * INF / 4) / 256; ++u)
    xdst[u * 256 + t] = xsrc[u * 256 + t];
  __syncthreads();

  const int c  = t & 127;
  const int rg = t >> 7;  // 0/1 -> rows rg*16 .. rg*16+15
  float acc[16];
  #pragma unroll
  for (int r = 0; r < 16; ++r) acc[r] = 0.f;
  for (int k = 0; k < INF; ++k) {
    float wv = W[k * OUTF + c];
    #pragma unroll
    for (int r = 0; r < 16; ++r) acc[r] += xs[rg * 16 + r][k] * wv;
  }
  #pragma unroll
  for (int r = 0; r < 16; ++r) hs[rg * 16 + r][c] = acc[r];
  __syncthreads();

  const int wv = t >> 6, lane = t & 63;
  for (int r = wv; r < 32; r += 4) {
    float h0 = hs[r][lane * 2], h1 = hs[r][lane * 2 + 1];
    float s1 = h0 * a[lane * 2] + h1 * a[lane * 2 + 1];
    float s2 = h0 * a[OUTF + lane * 2] + h1 * a[OUTF + lane * 2 + 1];
    #pragma unroll
    for (int off = 32; off; off >>= 1) {
      s1 += __shfl_down(s1, off);
      s2 += __shfl_down(s2, off);
    }
    if (lane == 0) { f1[i0 + r] = s1 * LOG2E; f2[i0 + r] = s2 * LOG2E; }
  }

  const int col = t >> 1, seg = t & 1;
  bf16x8 v0, v1;
  #pragma unroll
  for (int r = 0; r < 8; ++r) v0[r] = (__bf16)hs[seg * 16 + r][col];
  #pragma unroll
  for (int r = 0; r < 8; ++r) v1[r] = (__bf16)hs[seg * 16 + 8 + r][col];
  __bf16* hdst = ht + (size_t)col * NROW + i0 + seg * 16;
  *reinterpret_cast<bf16x8*>(hdst)     = v0;
  *reinterpret_cast<bf16x8*>(hdst + 8) = v1;
}

// ---------------------------------------------------------------------------
// k2: one wave per row, 512 cols/iter (2 int4 NT loads in flight). Nibble-
// pack mask via __shfl_xor OR-reduce; row sum of masked exp2.
// grid: NROW/4 blocks, 256 threads
// ---------------------------------------------------------------------------
__global__ __launch_bounds__(256) void k2(const int* __restrict__ adj,
                                          const float* __restrict__ f1,
                                          const float* __restrict__ f2,
                                          u64* __restrict__ mask,
                                          float* __restrict__ s) {
  const int row  = blockIdx.x * 4 + (threadIdx.x >> 6);
  const int lane = threadIdx.x & 63;
  const float f1i = f1[row];
  const i32x4* arow = reinterpret_cast<const i32x4*>(adj + (size_t)row * NROW);
  const f32x4* f2v  = reinterpret_cast<const f32x4*>(f2);

  float acc = 0.f;
  for (int it = 0; it < NROW / 512; ++it) {
    i32x4 av0 = __builtin_nontemporal_load(arow + it * 128 + lane);
    i32x4 av1 = __builtin_nontemporal_load(arow + it * 128 + 64 + lane);
    f32x4 fv0 = f2v[it * 128 + lane];
    f32x4 fv1 = f2v[it * 128 + 64 + lane];

    unsigned nib0 = (av0[0] > 0) | ((av0[1] > 0) << 1) | ((av0[2] > 0) << 2) |
                    ((av0[3] > 0) << 3);
    unsigned nib1 = (av1[0] > 0) | ((av1[1] > 0) << 1) | ((av1[2] > 0) << 2) |
                    ((av1[3] > 0) << 3);
    #pragma unroll
    for (int b = 0; b < 4; ++b) {
      float e0 = f1i + fv0[b];
      e0 = e0 > 0.f ? e0 : 0.01f * e0;
      acc += ((nib0 >> b) & 1u) ? __builtin_exp2f(e0) : 0.f;
      float e1 = f1i + fv1[b];
      e1 = e1 > 0.f ? e1 : 0.01f * e1;
      acc += ((nib1 >> b) & 1u) ? __builtin_exp2f(e1) : 0.f;
    }
    u64 m0 = (u64)nib0 << (4 * (lane & 15));
    u64 m1 = (u64)nib1 << (4 * (lane & 15));
    #pragma unroll
    for (int d = 1; d < 16; d <<= 1) {
      m0 |= __shfl_xor(m0, d);
      m1 |= __shfl_xor(m1, d);
    }
    if ((lane & 15) == 0) {
      mask[(size_t)row * 128 + it * 8 + (lane >> 4)]     = m0;
      mask[(size_t)row * 128 + it * 8 + 4 + (lane >> 4)] = m1;
    }
  }
  #pragma unroll
  for (int off = 32; off; off >>= 1) acc += __shfl_down(acc, off);
  if (lane == 0) s[row] = acc;
}

// ---------------------------------------------------------------------------
// k3: fused att-write + PV. 64 rows x 1024-col chunk per block.
// MFMA path: afrag in MFMA lane layout (row=lr, cols lc*8..), as before.
// STORE path: separate lane assignment — lane l stores row g*4+(l>>4),
// cols (l&15)*4..+3, one 16B store per g. Each store instruction covers
// 4 rows x 256B fully CONTIGUOUS = full 64B lines -> L2 acks fast, no
// partial-line merge stall in the in-order vmcnt queue. P recomputed from
// LDS f2s/ms for this layout (16 extra exp2/lane/iter, ~50 cyc — cheap).
// grid: (NROW/64)*KSPLIT blocks, 256 threads
// ---------------------------------------------------------------------------
__global__ __launch_bounds__(256, 4) void k3(const __bf16* __restrict__ ht,
                                             const float* __restrict__ f1,
                                             const float* __restrict__ f2,
                                             const float* __restrict__ sum,
                                             const u64* __restrict__ mask,
                                             float* __restrict__ out0,
                                             float* __restrict__ att) {
  __shared__ float f2s[KCHUNK];  // 4 KB
  __shared__ u64 ms[64][17];     // 8.5 KB (pad 17: conflict-free b64 reads)
  const int mb = blockIdx.x / KSPLIT;
  const int ks = blockIdx.x % KSPLIT;
  const int t    = threadIdx.x;
  const int w    = t >> 6;
  const int lane = t & 63;
  const int lr = lane & 15;
  const int lc = lane >> 4;
  const int row0 = mb * 64 + w * 16;
  const int arow = row0 + lr;
  const int j0 = ks * KCHUNK;

  {
    const f32x4* src = reinterpret_cast<const f32x4*>(f2 + j0);
    reinterpret_cast<f32x4*>(f2s)[t] = src[t];  // 256 x 16B = 4 KB
    const int r = t >> 2, q = (t & 3) * 4;
    const u64* msrc = mask + (size_t)(mb * 64 + r) * 128 + (j0 >> 6) + q;
    ms[r][q]     = msrc[0];
    ms[r][q + 1] = msrc[1];
    ms[r][q + 2] = msrc[2];
    ms[r][q + 3] = msrc[3];
  }
  __syncthreads();

  const float f1r  = f1[arow];
  const int   rloc = w * 16 + lr;
  const __bf16* hbase = ht + (size_t)lr * NROW + j0 + lc * 8;

  // store-path per-lane constants: rows g*4 + (lane>>4), g = 0..3
  const int srow = lane >> 4;           // 0..3 within each 4-row group
  const int scol = (lane & 15) * 4;     // float col offset within 64-col tile
  float f1g[4], isg[4];
  #pragma unroll
  for (int g = 0; g < 4; ++g) {
    const int r = row0 + g * 4 + srow;
    f1g[g] = f1[r];
    isg[g] = 1.0f / sum[r];
  }

  f32x4 acc[8];
  #pragma unroll
  for (int n = 0; n < 8; ++n) acc[n] = (f32x4){0.f, 0.f, 0.f, 0.f};

  for (int kk = 0; kk < KCHUNK; kk += 64) {
    // ---- MFMA A-fragments (MFMA lane layout) ----
    const u64 mw = ms[rloc][kk >> 6];
    bf16x8 afrag[2];
    #pragma unroll
    for (int h = 0; h < 2; ++h) {
      const unsigned bits = (unsigned)(mw >> (h * 32 + lc * 8)) & 0xFFu;
      const int base = kk + h * 32 + lc * 8;
      #pragma unroll
      for (int i2 = 0; i2 < 8; ++i2) {
        float e = f1r + f2s[base + i2];
        e = e > 0.f ? e : 0.01f * e;
        afrag[h][i2] = (__bf16)(((bits >> i2) & 1u) ? __builtin_exp2f(e) : 0.f);
      }
    }
    // ---- b-loads + MFMA ----
    #pragma unroll
    for (int n = 0; n < 8; ++n) {
      const __bf16* hb = hbase + (size_t)(n * 16) * NROW + kk;
      bf16x8 b0 = *reinterpret_cast<const bf16x8*>(hb);
      bf16x8 b1 = *reinterpret_cast<const bf16x8*>(hb + 32);
      acc[n] = __builtin_amdgcn_mfma_f32_16x16x32_bf16(afrag[0], b0, acc[n], 0, 0, 0);
      acc[n] = __builtin_amdgcn_mfma_f32_16x16x32_bf16(afrag[1], b1, acc[n], 0, 0, 0);
    }
    // ---- att stores (contiguous lane layout, recomputed P) ----
    const f32x4 fv = reinterpret_cast<const f32x4*>(f2s)[(kk >> 2) + (lane & 15)];
    #pragma unroll
    for (int g = 0; g < 4; ++g) {
      const unsigned bits =
          (unsigned)(ms[w * 16 + g * 4 + srow][kk >> 6] >> scol) & 0xFu;
      f32x4 o;
      #pragma unroll
      for (int b = 0; b < 4; ++b) {
        float e = f1g[g] + fv[b];
        e = e > 0.f ? e : 0.01f * e;
        o[b] = ((bits >> b) & 1u) ? __builtin_exp2f(e) * isg[g] : 0.f;
      }
      float* adst =
          att + (size_t)(row0 + g * 4 + srow) * NROW + j0 + kk + scol;
      *reinterpret_cast<f32x4*>(adst) = o;
    }
  }

  float inv_sD[4];
  #pragma unroll
  for (int i2 = 0; i2 < 4; ++i2) inv_sD[i2] = 1.0f / sum[row0 + lc * 4 + i2];
  #pragma unroll
  for (int n = 0; n < 8; ++n) {
    #pragma unroll
    for (int i2 = 0; i2 < 4; ++i2) {
      atomicAdd(&out0[(size_t)(row0 + lc * 4 + i2) * OUTF + n * 16 + lr],
                acc[n][i2] * inv_sD[i2]);
    }
  }
}

// ---------------------------------------------------------------------------
extern "C" void kernel_launch(void* const* d_in, const int* in_sizes, int n_in,
                              void* d_out, int out_size, void* d_ws, size_t ws_size,
                              hipStream_t stream) {
  const float* x   = (const float*)d_in[0];
  const int*   adj = (const int*)d_in[1];
  const float* W   = (const float*)d_in[2];
  const float* a   = (const float*)d_in[3];

  float* out0 = (float*)d_out;                       // 8192 x 128
  float* att  = (float*)d_out + (size_t)NROW * OUTF; // 8192 x 8192

  char* ws = (char*)d_ws;
  __bf16* ht = (__bf16*)ws;                                         // 2 MB
  u64* mask = (u64*)(ws + (2 << 20));                               // 8 MB
  float* f1 = (float*)(ws + (10 << 20));
  float* f2 = (float*)(ws + (10 << 20) + 32 * 1024);
  float* s  = (float*)(ws + (10 << 20) + 64 * 1024);

  hipMemsetAsync(out0, 0, (size_t)NROW * OUTF * sizeof(float), stream);
  k1<<<NROW / 32, 256, 0, stream>>>(x, W, a, ht, f1, f2);
  k2<<<NROW / 4, 256, 0, stream>>>(adj, f1, f2, mask, s);
  k3<<<(NROW / 64) * KSPLIT, 256, 0, stream>>>(ht, f1, f2, s, mask, out0, att);
}